// Round 2
// baseline (2603.271 us; speedup 1.0000x reference)
//
#include <hip/hip_runtime.h>
#include <stdint.h>

// Problem constants (from reference)
#define N_VOX    200000
#define C_CH     64
#define K_OFF    27
#define M_PAIRS  100000
#define KM       (K_OFF * M_PAIRS)              // 2,700,000 pairs
#define TILE     128                            // output voxels per block (o>>7)
#define NT       ((N_VOX + TILE - 1) / TILE)    // 1563 tiles
#define NB       (NT * K_OFF)                   // 42201 (tile,k) buckets
#define OLDS_STRIDE 68                          // padded LDS row stride (floats)
#define WBN      (K_OFF * 4096)                 // 110592 weight elems per layer
#define EPS_BN   1e-5f
#define NW       8                              // waves per conv block
#define PLCAP    2304                           // staged payload capacity (mean 1727, sigma~41)
#define TCCAP    (PLCAP / 16 + K_OFF)           // 171 chunk-map capacity
#define PADV     ((unsigned)(TILE << 18))       // pad payload: iidx=0, oloc=dummy row

typedef __attribute__((ext_vector_type(8))) short   short8_t;  // 8 x bf16
typedef __attribute__((ext_vector_type(4))) float   f32x4;
typedef __attribute__((ext_vector_type(4))) unsigned short u16x4;

__device__ __forceinline__ unsigned short f2bf(float f) {
    union { float f; unsigned u; } v; v.f = f;
    unsigned r = v.u + 0x7FFFu + ((v.u >> 16) & 1u);   // RTNE
    return (unsigned short)(r >> 16);
}

// ---------- prep (+hist fused): x->bf16, w->B-frag layout, BN fold, bucket histogram ----------
__global__ void prep_kernel(const float* __restrict__ x,
                            const float* __restrict__ w1, const float* __restrict__ w2,
                            const float* __restrict__ g1, const float* __restrict__ b1,
                            const float* __restrict__ m1, const float* __restrict__ v1,
                            const float* __restrict__ g2, const float* __restrict__ b2,
                            const float* __restrict__ m2, const float* __restrict__ v2,
                            const int* __restrict__ out_map,
                            unsigned short* __restrict__ xb,
                            unsigned short* __restrict__ wb1, unsigned short* __restrict__ wb2,
                            float* __restrict__ sb1, float* __restrict__ sb2,
                            int* __restrict__ cnt)
{
    long i = (long)blockIdx.x * blockDim.x + threadIdx.x;
    const long XBN = (long)N_VOX * C_CH;   // 12.8M
    if (i < XBN) { xb[i] = f2bf(x[i]); return; }
    long j = i - XBN;
    if (j < 2 * WBN) {
        const float* w = (j < WBN) ? w1 : w2;
        unsigned short* wb = (j < WBN) ? wb1 : wb2;
        int o = (int)(j >= WBN ? j - WBN : j);
        int k   = o >> 12;
        int rem = o & 4095;
        int t  = rem >> 11;
        int sl = (rem >> 9) & 3;
        int d  = (rem >> 3) & 63;
        int jj = rem & 7;
        int c  = t * 32 + sl * 8 + jj;
        wb[o] = f2bf(w[k * 4096 + c * 64 + d]);
        return;
    }
    j -= 2 * WBN;
    if (j < 64) {
        float s = g1[j] * rsqrtf(v1[j] + EPS_BN);
        sb1[j] = s; sb1[64 + j] = b1[j] - m1[j] * s;
        return;
    }
    if (j < 128) {
        int c = (int)j - 64;
        float s = g2[c] * rsqrtf(v2[c] + EPS_BN);
        sb2[c] = s; sb2[64 + c] = b2[c] - m2[c] * s;
        return;
    }
    j -= 128;
    if (j < KM) {   // histogram
        int p = (int)j;
        int k = p / M_PAIRS;
        int o = out_map[p];
        atomicAdd(&cnt[(o >> 7) * K_OFF + k], 1);
    }
}

// ---------------- exclusive scan of bucket counts ----------------
__global__ void scan_kernel(const int* __restrict__ cnt, int* __restrict__ offs) {
    __shared__ int part[1024];
    int t = threadIdx.x;
    const int SEG = (NB + 1023) / 1024;   // 42
    int beg = t * SEG;
    int s = 0;
    for (int i = 0; i < SEG; ++i) { int idx = beg + i; if (idx < NB) s += cnt[idx]; }
    part[t] = s;
    __syncthreads();
    for (int d = 1; d < 1024; d <<= 1) {
        int v = (t >= d) ? part[t - d] : 0;
        __syncthreads();
        part[t] += v;
        __syncthreads();
    }
    int run = (t > 0) ? part[t - 1] : 0;
    for (int i = 0; i < SEG; ++i) {
        int idx = beg + i;
        if (idx <= NB) offs[idx] = run;
        if (idx < NB) run += cnt[idx];
    }
}

// payload: in_idx (18 bits) | out_local (bits 18..25)
__global__ void scatter_kernel(const int* __restrict__ in_map, const int* __restrict__ out_map,
                               const int* __restrict__ offs, int* __restrict__ cursor,
                               unsigned int* __restrict__ payload)
{
    int p = blockIdx.x * 256 + threadIdx.x;
    if (p >= KM) return;
    int k = p / M_PAIRS;
    int o = out_map[p];
    int key = (o >> 7) * K_OFF + k;
    int pos = offs[key] + atomicAdd(&cursor[key], 1);
    payload[pos] = (unsigned)in_map[p] | ((unsigned)(o & (TILE - 1)) << 18);
}

// ---------------- fused sparse-conv (+BN [+ReLU] [+residual]) ----------------
// Block = 128-voxel output tile, 8 waves. Payload/offsets/chunk-map prestaged in LDS.
// Flat chunk worklist; depth-2 software pipeline on the A-gather and B loads.
template<int LAYER>
__global__ __launch_bounds__(512, 4) void conv_kernel(
    const unsigned short* __restrict__ xin,     // bf16 rows [N][64]
    const unsigned short* __restrict__ wb,      // pre-swizzled bf16 weights
    const unsigned int* __restrict__ payload,
    const int* __restrict__ offs,
    const float* __restrict__ sb,               // [0:64) scale, [64:128) shift
    const float* __restrict__ xres,             // LAYER==1: residual (f32)
    void* __restrict__ outp)                    // LAYER==0: bf16 h; LAYER==1: f32 d_out
{
    __shared__ float olds[(TILE + 1) * OLDS_STRIDE];   // 35.1 KB (+1 dummy row)
    __shared__ int soffs[K_OFF + 1];
    __shared__ int scum[K_OFF + 1];
    __shared__ unsigned char ckk[TCCAP];
    __shared__ unsigned int plds[PLCAP];

    const int tile = blockIdx.x;
    const int tid = threadIdx.x;

    if (tid <= K_OFF) soffs[tid] = offs[tile * K_OFF + tid];
    {
        f32x4* o4 = (f32x4*)olds;
        const int n4 = (TILE + 1) * OLDS_STRIDE / 4;
        f32x4 z = {0.f, 0.f, 0.f, 0.f};
        for (int i = tid; i < n4; i += 512) o4[i] = z;
    }
    __syncthreads();

    const int p0 = soffs[0];
    const int total = soffs[K_OFF] - p0;
    if (tid == 0) {
        int run = 0;
        #pragma unroll 1
        for (int k = 0; k < K_OFF; ++k) {
            scum[k] = run;
            run += (soffs[k + 1] - soffs[k] + 15) >> 4;
        }
        scum[K_OFF] = run;
    }
    {
        int stot = total < PLCAP ? total : PLCAP;
        for (int i = tid; i < stot; i += 512) plds[i] = payload[p0 + i];
    }
    __syncthreads();
    if (tid < K_OFF) {
        int c0 = scum[tid], c1 = scum[tid + 1];
        for (int c = c0; c < c1; ++c) if (c < TCCAP) ckk[c] = (unsigned char)tid;
    }
    __syncthreads();

    const int TC = scum[K_OFF];
    const int lane  = tid & 63;
    const int wid   = tid >> 6;
    const int r     = lane & 15;
    const int sfour = lane >> 4;

    auto load_stage = [&](int t, unsigned& pl, short8_t& A0, short8_t& A1,
                          short8_t (&B)[2][4]) {
        int k;
        if (t < TCCAP) k = ckk[t];
        else { k = 0; while (k < K_OFF - 1 && scum[k + 1] <= t) ++k; }
        int cs  = soffs[k];
        int cnt = soffs[k + 1] - cs;
        int ii  = (t - scum[k]) * 16 + r;
        unsigned p = PADV;
        if (ii < cnt) {
            int rel = cs - p0 + ii;
            p = (rel < PLCAP) ? plds[rel] : payload[p0 + rel];
        }
        pl = p;
        int iidx = (int)(p & 0x3FFFFu);
        const short8_t* xrow = (const short8_t*)(xin + (size_t)iidx * 64);
        A0 = xrow[sfour];
        A1 = xrow[4 + sfour];
        const short8_t* wbk = (const short8_t*)(wb + k * 4096);
        #pragma unroll
        for (int tt = 0; tt < 2; ++tt)
            #pragma unroll
            for (int n = 0; n < 4; ++n)
                B[tt][n] = wbk[(tt * 4 + sfour) * 64 + n * 16 + r];
    };

    unsigned pl_n; short8_t A0_n, A1_n, B_n[2][4];
    int t = wid;
    if (t < TC) load_stage(t, pl_n, A0_n, A1_n, B_n);
    #pragma unroll 1
    for (; t < TC; t += NW) {
        unsigned pl_c = pl_n;
        short8_t A0_c = A0_n, A1_c = A1_n;
        short8_t B_c[2][4];
        #pragma unroll
        for (int tt = 0; tt < 2; ++tt)
            #pragma unroll
            for (int n = 0; n < 4; ++n) B_c[tt][n] = B_n[tt][n];

        int tn = t + NW;
        if (tn < TC) load_stage(tn, pl_n, A0_n, A1_n, B_n);   // depth-2: next in flight

        f32x4 acc[4] = {{0,0,0,0},{0,0,0,0},{0,0,0,0},{0,0,0,0}};
        #pragma unroll
        for (int n = 0; n < 4; ++n) {
            acc[n] = __builtin_amdgcn_mfma_f32_16x16x32_bf16(A0_c, B_c[0][n], acc[n], 0, 0, 0);
            acc[n] = __builtin_amdgcn_mfma_f32_16x16x32_bf16(A1_c, B_c[1][n], acc[n], 0, 0, 0);
        }

        // D layout: col = n*16 + r (channel), row = sfour*4 + j (pair slot in chunk)
        int oloc = (int)(pl_c >> 18);
        #pragma unroll
        for (int j = 0; j < 4; ++j) {
            int drow = sfour * 4 + j;
            int ol = __shfl(oloc, drow, 64);     // pad rows -> dummy row (TILE)
            float* rowp = &olds[ol * OLDS_STRIDE];
            #pragma unroll
            for (int n = 0; n < 4; ++n)
                atomicAdd(&rowp[n * 16 + r], acc[n][j]);
        }
    }
    __syncthreads();

    // epilogue: BN fold (+relu / +residual+relu), vectorized write
    const int row0 = tile * TILE;
    int rows = N_VOX - row0; if (rows > TILE) rows = TILE;
    const f32x4* sc4 = (const f32x4*)sb;
    const f32x4* bi4 = (const f32x4*)(sb + 64);
    for (int e4 = tid; e4 < rows * 16; e4 += 512) {
        int row = e4 >> 4, q = e4 & 15;
        f32x4 v = *(const f32x4*)&olds[row * OLDS_STRIDE + q * 4];
        v = v * sc4[q] + bi4[q];
        int g4 = (row0 + row) * 16 + q;
        if (LAYER == 0) {
            u16x4 h;
            #pragma unroll
            for (int ii = 0; ii < 4; ++ii) {
                float f = v[ii] > 0.f ? v[ii] : 0.f;
                h[ii] = f2bf(f);
            }
            ((u16x4*)outp)[g4] = h;
        } else {
            f32x4 xr = ((const f32x4*)xres)[g4];
            v = v + xr;
            #pragma unroll
            for (int ii = 0; ii < 4; ++ii) v[ii] = v[ii] > 0.f ? v[ii] : 0.f;
            ((f32x4*)outp)[g4] = v;
        }
    }
}

// ---------------- launch ----------------
extern "C" void kernel_launch(void* const* d_in, const int* in_sizes, int n_in,
                              void* d_out, int out_size, void* d_ws, size_t ws_size,
                              hipStream_t stream)
{
    const float* x  = (const float*)d_in[0];
    const float* w1 = (const float*)d_in[1];
    const float* w2 = (const float*)d_in[2];
    const float* g1 = (const float*)d_in[3];
    const float* b1 = (const float*)d_in[4];
    const float* m1 = (const float*)d_in[5];
    const float* v1 = (const float*)d_in[6];
    const float* g2 = (const float*)d_in[7];
    const float* b2 = (const float*)d_in[8];
    const float* m2 = (const float*)d_in[9];
    const float* v2 = (const float*)d_in[10];
    const int* in_map  = (const int*)d_in[11];
    const int* out_map = (const int*)d_in[12];

    char* ws = (char*)d_ws;
    size_t off = 0;
    auto alloc = [&](size_t bytes) -> void* {
        void* p = ws + off;
        off = (off + bytes + 255) & ~(size_t)255;
        return p;
    };
    int*            cnt     = (int*)alloc((size_t)NB * 4);
    int*            cursor  = (int*)alloc((size_t)NB * 4);
    int*            offs    = (int*)alloc((size_t)(NB + 1) * 4);
    float*          sb1     = (float*)alloc(128 * 4);
    float*          sb2     = (float*)alloc(128 * 4);
    unsigned short* wb1     = (unsigned short*)alloc((size_t)WBN * 2);
    unsigned short* wb2     = (unsigned short*)alloc((size_t)WBN * 2);
    unsigned int*   payload = (unsigned int*)alloc((size_t)KM * 4);
    unsigned short* xb      = (unsigned short*)alloc((size_t)N_VOX * C_CH * 2);
    unsigned short* hb      = (unsigned short*)alloc((size_t)N_VOX * C_CH * 2);

    // zero cnt + cursor (contiguous region)
    size_t zlen = (size_t)((char*)cursor - (char*)cnt) + (size_t)NB * 4;
    hipMemsetAsync(cnt, 0, zlen, stream);

    const long TOT = (long)N_VOX * C_CH + 2 * WBN + 128 + KM;
    int prep_blocks = (int)((TOT + 255) / 256);
    prep_kernel<<<prep_blocks, 256, 0, stream>>>(x, w1, w2, g1, b1, m1, v1,
                                                 g2, b2, m2, v2, out_map,
                                                 xb, wb1, wb2, sb1, sb2, cnt);

    scan_kernel<<<1, 1024, 0, stream>>>(cnt, offs);

    int pair_blocks = (KM + 255) / 256;
    scatter_kernel<<<pair_blocks, 256, 0, stream>>>(in_map, out_map, offs, cursor, payload);

    conv_kernel<0><<<NT, 512, 0, stream>>>(xb, wb1, payload, offs, sb1, nullptr, hb);
    conv_kernel<1><<<NT, 512, 0, stream>>>(hb, wb2, payload, offs, sb2, x, d_out);
}

// Round 3
// 2597.472 us; speedup vs baseline: 1.0022x; 1.0022x over previous
//
#include <hip/hip_runtime.h>
#include <stdint.h>

// Problem constants (from reference)
#define N_VOX    200000
#define C_CH     64
#define K_OFF    27
#define M_PAIRS  100000
#define KM       (K_OFF * M_PAIRS)              // 2,700,000 pairs
#define TILE     128                            // output voxels per block (o>>7)
#define NT       ((N_VOX + TILE - 1) / TILE)    // 1563 tiles
#define NB       (NT * K_OFF)                   // 42201 (tile,k) buckets
#define OLDS_STRIDE 68                          // padded LDS row stride (floats)
#define WBN      (K_OFF * 4096)                 // 110592 weight elems per layer
#define EPS_BN   1e-5f
#define NW       8                              // waves per conv block
#define PLCAP    2304                           // staged payload capacity (mean 1727, sigma~41)
#define TCCAP    (PLCAP / 16 + K_OFF)           // 171 chunk-map capacity
#define PADV     ((unsigned)(TILE << 18))       // pad payload: iidx=0, oloc=dummy row

typedef __attribute__((ext_vector_type(8))) short   short8_t;  // 8 x bf16
typedef __attribute__((ext_vector_type(4))) float   f32x4;
typedef __attribute__((ext_vector_type(4))) unsigned short u16x4;

__device__ __forceinline__ unsigned short f2bf(float f) {
    union { float f; unsigned u; } v; v.f = f;
    unsigned r = v.u + 0x7FFFu + ((v.u >> 16) & 1u);   // RTNE
    return (unsigned short)(r >> 16);
}

// ---------- prep (+hist fused): x->bf16, w->B-frag layout, BN fold, bucket histogram ----------
__global__ void prep_kernel(const float* __restrict__ x,
                            const float* __restrict__ w1, const float* __restrict__ w2,
                            const float* __restrict__ g1, const float* __restrict__ b1,
                            const float* __restrict__ m1, const float* __restrict__ v1,
                            const float* __restrict__ g2, const float* __restrict__ b2,
                            const float* __restrict__ m2, const float* __restrict__ v2,
                            const int* __restrict__ out_map,
                            unsigned short* __restrict__ xb,
                            unsigned short* __restrict__ wb1, unsigned short* __restrict__ wb2,
                            float* __restrict__ sb1, float* __restrict__ sb2,
                            int* __restrict__ cnt)
{
    long i = (long)blockIdx.x * blockDim.x + threadIdx.x;
    const long XBN = (long)N_VOX * C_CH;   // 12.8M
    if (i < XBN) { xb[i] = f2bf(x[i]); return; }
    long j = i - XBN;
    if (j < 2 * WBN) {
        const float* w = (j < WBN) ? w1 : w2;
        unsigned short* wb = (j < WBN) ? wb1 : wb2;
        int o = (int)(j >= WBN ? j - WBN : j);
        int k   = o >> 12;
        int rem = o & 4095;
        int t  = rem >> 11;
        int sl = (rem >> 9) & 3;
        int d  = (rem >> 3) & 63;
        int jj = rem & 7;
        int c  = t * 32 + sl * 8 + jj;
        wb[o] = f2bf(w[k * 4096 + c * 64 + d]);
        return;
    }
    j -= 2 * WBN;
    if (j < 64) {
        float s = g1[j] * rsqrtf(v1[j] + EPS_BN);
        sb1[j] = s; sb1[64 + j] = b1[j] - m1[j] * s;
        return;
    }
    if (j < 128) {
        int c = (int)j - 64;
        float s = g2[c] * rsqrtf(v2[c] + EPS_BN);
        sb2[c] = s; sb2[64 + c] = b2[c] - m2[c] * s;
        return;
    }
    j -= 128;
    if (j < KM) {   // histogram
        int p = (int)j;
        int k = p / M_PAIRS;
        int o = out_map[p];
        atomicAdd(&cnt[(o >> 7) * K_OFF + k], 1);
    }
}

// ---------------- exclusive scan of bucket counts ----------------
__global__ void scan_kernel(const int* __restrict__ cnt, int* __restrict__ offs) {
    __shared__ int part[1024];
    int t = threadIdx.x;
    const int SEG = (NB + 1023) / 1024;   // 42
    int beg = t * SEG;
    int s = 0;
    for (int i = 0; i < SEG; ++i) { int idx = beg + i; if (idx < NB) s += cnt[idx]; }
    part[t] = s;
    __syncthreads();
    for (int d = 1; d < 1024; d <<= 1) {
        int v = (t >= d) ? part[t - d] : 0;
        __syncthreads();
        part[t] += v;
        __syncthreads();
    }
    int run = (t > 0) ? part[t - 1] : 0;
    for (int i = 0; i < SEG; ++i) {
        int idx = beg + i;
        if (idx <= NB) offs[idx] = run;
        if (idx < NB) run += cnt[idx];
    }
}

// payload: in_idx (18 bits) | out_local (bits 18..25)
__global__ void scatter_kernel(const int* __restrict__ in_map, const int* __restrict__ out_map,
                               const int* __restrict__ offs, int* __restrict__ cursor,
                               unsigned int* __restrict__ payload)
{
    int p = blockIdx.x * 256 + threadIdx.x;
    if (p >= KM) return;
    int k = p / M_PAIRS;
    int o = out_map[p];
    int key = (o >> 7) * K_OFF + k;
    int pos = offs[key] + atomicAdd(&cursor[key], 1);
    payload[pos] = (unsigned)in_map[p] | ((unsigned)(o & (TILE - 1)) << 18);
}

// ---------------- fused sparse-conv (+BN [+ReLU] [+residual]) ----------------
// Block = 128-voxel output tile, 8 waves, contiguous chunk range per wave.
// Depth-4 statically-indexed software pipeline on the A-gather (counted vmcnt via compiler).
template<int LAYER>
__global__ __launch_bounds__(512, 4) void conv_kernel(
    const unsigned short* __restrict__ xin,     // bf16 rows [N][64]
    const unsigned short* __restrict__ wb,      // pre-swizzled bf16 weights
    const unsigned int* __restrict__ payload,
    const int* __restrict__ offs,
    const float* __restrict__ sb,               // [0:64) scale, [64:128) shift
    const float* __restrict__ xres,             // LAYER==1: residual (f32)
    void* __restrict__ outp)                    // LAYER==0: bf16 h; LAYER==1: f32 d_out
{
    __shared__ float olds[(TILE + 1) * OLDS_STRIDE];   // 35.1 KB (+1 dummy row)
    __shared__ int soffs[K_OFF + 1];
    __shared__ int scum[K_OFF + 1];
    __shared__ int desc[TCCAP];                        // k | relbase<<5 | relend<<18
    __shared__ unsigned int plds[PLCAP];

    const int tile = blockIdx.x;
    const int tid = threadIdx.x;

    if (tid <= K_OFF) soffs[tid] = offs[tile * K_OFF + tid];
    {
        f32x4* o4 = (f32x4*)olds;
        const int n4 = (TILE + 1) * OLDS_STRIDE / 4;
        f32x4 z = {0.f, 0.f, 0.f, 0.f};
        for (int i = tid; i < n4; i += 512) o4[i] = z;
    }
    __syncthreads();

    const int p0 = soffs[0];
    const int total = soffs[K_OFF] - p0;
    // wave-parallel prefix over 27 bucket chunk-counts (lanes 0..31 of wave 0)
    if (tid < 32) {
        int c = (tid < K_OFF) ? ((soffs[tid + 1] - soffs[tid] + 15) >> 4) : 0;
        int v = c;
        #pragma unroll
        for (int d = 1; d < 32; d <<= 1) {
            int u = __shfl_up(v, d, 32);
            if (tid >= d) v += u;
        }
        if (tid == 0) scum[0] = 0;
        if (tid < K_OFF) scum[tid + 1] = v;
    }
    {
        int stot = total < PLCAP ? total : PLCAP;
        for (int i = tid; i < stot; i += 512) plds[i] = payload[p0 + i];
    }
    __syncthreads();
    // build packed chunk descriptors (one bucket per thread)
    if (tid < K_OFF) {
        int c0 = scum[tid], c1 = scum[tid + 1];
        int base = soffs[tid] - p0;
        int end  = soffs[tid + 1] - p0;
        for (int c = c0; c < c1; ++c)
            if (c < TCCAP) desc[c] = tid | ((base + (c - c0) * 16) << 5) | (end << 18);
    }
    __syncthreads();

    const int TC = scum[K_OFF];
    const int lane  = tid & 63;
    const int wid   = tid >> 6;
    const int r     = lane & 15;
    const int sfour = lane >> 4;

    // contiguous chunk range for this wave
    const int CPW = (TC + NW - 1) >> 3;
    int w0 = wid * CPW; if (w0 > TC) w0 = TC;
    int w1 = w0 + CPW;  if (w1 > TC) w1 = TC;

    // pipeline stage state (statically indexed only)
    short8_t A0s[4], A1s[4];
    unsigned pls[4];
    int      kks[4];
    short8_t B0[4], B1[4];
    int kcur = -1;

#define ISSUE(S, TT) do {                                                   \
        int _t = (TT);                                                      \
        if (_t < w1) {                                                      \
            int _d;                                                         \
            if (_t < TCCAP) _d = desc[_t];                                  \
            else {                                                          \
                int _k = 0;                                                 \
                while (_k < K_OFF - 1 && scum[_k + 1] <= _t) ++_k;          \
                _d = _k | (((soffs[_k] - p0) + (_t - scum[_k]) * 16) << 5)  \
                        | ((soffs[_k + 1] - p0) << 18);                     \
            }                                                               \
            kks[S] = _d & 31;                                               \
            int _rb = (_d >> 5) & 0x1FFF;                                   \
            int _re = _d >> 18;                                             \
            int _ii = _rb + r;                                              \
            unsigned _p = PADV;                                             \
            if (_ii < _re)                                                  \
                _p = (_ii < PLCAP) ? plds[_ii] : payload[p0 + _ii];         \
            pls[S] = _p;                                                    \
            const short8_t* _xr =                                           \
                (const short8_t*)(xin + (size_t)(_p & 0x3FFFFu) * 64);      \
            A0s[S] = _xr[sfour];                                            \
            A1s[S] = _xr[4 + sfour];                                        \
        }                                                                   \
    } while (0)

#define CONSUME(S) do {                                                     \
        int _kk = __builtin_amdgcn_readfirstlane(kks[S]);                   \
        if (_kk != kcur) {                                                  \
            kcur = _kk;                                                     \
            const short8_t* _wbk = (const short8_t*)(wb + kcur * 4096);     \
            _Pragma("unroll")                                               \
            for (int n = 0; n < 4; ++n) {                                   \
                B0[n] = _wbk[sfour * 64 + n * 16 + r];                      \
                B1[n] = _wbk[(4 + sfour) * 64 + n * 16 + r];                \
            }                                                               \
        }                                                                   \
        f32x4 acc[4] = {{0,0,0,0},{0,0,0,0},{0,0,0,0},{0,0,0,0}};           \
        _Pragma("unroll")                                                   \
        for (int n = 0; n < 4; ++n) {                                       \
            acc[n] = __builtin_amdgcn_mfma_f32_16x16x32_bf16(A0s[S], B0[n], acc[n], 0, 0, 0); \
            acc[n] = __builtin_amdgcn_mfma_f32_16x16x32_bf16(A1s[S], B1[n], acc[n], 0, 0, 0); \
        }                                                                   \
        int _ol0 = (int)(pls[S] >> 18);                                     \
        _Pragma("unroll")                                                   \
        for (int j = 0; j < 4; ++j) {                                       \
            int _dr = sfour * 4 + j;                                        \
            int _ol = __shfl(_ol0, _dr, 64);                                \
            float* _rp = &olds[_ol * OLDS_STRIDE];                          \
            _Pragma("unroll")                                               \
            for (int n = 0; n < 4; ++n)                                     \
                atomicAdd(&_rp[n * 16 + r], acc[n][j]);                     \
        }                                                                   \
    } while (0)

#define STAGE(S) do {                                                       \
        int _tc = i + (S);                                                  \
        if (_tc < w1) { CONSUME(S); ISSUE(S, _tc + 4); }                    \
    } while (0)

    // prologue: fill 4 stages
    ISSUE(0, w0 + 0);
    ISSUE(1, w0 + 1);
    ISSUE(2, w0 + 2);
    ISSUE(3, w0 + 3);

    #pragma unroll 1
    for (int i = w0; i < w1; i += 4) {
        STAGE(0);
        STAGE(1);
        STAGE(2);
        STAGE(3);
    }
#undef ISSUE
#undef CONSUME
#undef STAGE

    __syncthreads();

    // epilogue: BN fold (+relu / +residual+relu), vectorized write
    const int row0 = tile * TILE;
    int rows = N_VOX - row0; if (rows > TILE) rows = TILE;
    const f32x4* sc4 = (const f32x4*)sb;
    const f32x4* bi4 = (const f32x4*)(sb + 64);
    for (int e4 = tid; e4 < rows * 16; e4 += 512) {
        int row = e4 >> 4, q = e4 & 15;
        f32x4 v = *(const f32x4*)&olds[row * OLDS_STRIDE + q * 4];
        v = v * sc4[q] + bi4[q];
        int g4 = (row0 + row) * 16 + q;
        if (LAYER == 0) {
            u16x4 h;
            #pragma unroll
            for (int ii = 0; ii < 4; ++ii) {
                float f = v[ii] > 0.f ? v[ii] : 0.f;
                h[ii] = f2bf(f);
            }
            ((u16x4*)outp)[g4] = h;
        } else {
            f32x4 xr = ((const f32x4*)xres)[g4];
            v = v + xr;
            #pragma unroll
            for (int ii = 0; ii < 4; ++ii) v[ii] = v[ii] > 0.f ? v[ii] : 0.f;
            ((f32x4*)outp)[g4] = v;
        }
    }
}

// ---------------- launch ----------------
extern "C" void kernel_launch(void* const* d_in, const int* in_sizes, int n_in,
                              void* d_out, int out_size, void* d_ws, size_t ws_size,
                              hipStream_t stream)
{
    const float* x  = (const float*)d_in[0];
    const float* w1 = (const float*)d_in[1];
    const float* w2 = (const float*)d_in[2];
    const float* g1 = (const float*)d_in[3];
    const float* b1 = (const float*)d_in[4];
    const float* m1 = (const float*)d_in[5];
    const float* v1 = (const float*)d_in[6];
    const float* g2 = (const float*)d_in[7];
    const float* b2 = (const float*)d_in[8];
    const float* m2 = (const float*)d_in[9];
    const float* v2 = (const float*)d_in[10];
    const int* in_map  = (const int*)d_in[11];
    const int* out_map = (const int*)d_in[12];

    char* ws = (char*)d_ws;
    size_t off = 0;
    auto alloc = [&](size_t bytes) -> void* {
        void* p = ws + off;
        off = (off + bytes + 255) & ~(size_t)255;
        return p;
    };
    int*            cnt     = (int*)alloc((size_t)NB * 4);
    int*            cursor  = (int*)alloc((size_t)NB * 4);
    int*            offs    = (int*)alloc((size_t)(NB + 1) * 4);
    float*          sb1     = (float*)alloc(128 * 4);
    float*          sb2     = (float*)alloc(128 * 4);
    unsigned short* wb1     = (unsigned short*)alloc((size_t)WBN * 2);
    unsigned short* wb2     = (unsigned short*)alloc((size_t)WBN * 2);
    unsigned int*   payload = (unsigned int*)alloc((size_t)KM * 4);
    unsigned short* xb      = (unsigned short*)alloc((size_t)N_VOX * C_CH * 2);
    unsigned short* hb      = (unsigned short*)alloc((size_t)N_VOX * C_CH * 2);

    // zero cnt + cursor (contiguous region)
    size_t zlen = (size_t)((char*)cursor - (char*)cnt) + (size_t)NB * 4;
    hipMemsetAsync(cnt, 0, zlen, stream);

    const long TOT = (long)N_VOX * C_CH + 2 * WBN + 128 + KM;
    int prep_blocks = (int)((TOT + 255) / 256);
    prep_kernel<<<prep_blocks, 256, 0, stream>>>(x, w1, w2, g1, b1, m1, v1,
                                                 g2, b2, m2, v2, out_map,
                                                 xb, wb1, wb2, sb1, sb2, cnt);

    scan_kernel<<<1, 1024, 0, stream>>>(cnt, offs);

    int pair_blocks = (KM + 255) / 256;
    scatter_kernel<<<pair_blocks, 256, 0, stream>>>(in_map, out_map, offs, cursor, payload);

    conv_kernel<0><<<NT, 512, 0, stream>>>(xb, wb1, payload, offs, sb1, nullptr, hb);
    conv_kernel<1><<<NT, 512, 0, stream>>>(hb, wb2, payload, offs, sb2, x, d_out);
}